// Round 4
// baseline (37864.893 us; speedup 1.0000x reference)
//
#include <hip/hip_runtime.h>
#include <math.h>

// AutoregTransformer D=512 HID=2048 NH=8 L=4 T=32 B=16, fp32 in/out.
// R4: ONE 1024-thread workgroup per batch (16 blocks total). Zero cross-block
// barriers in the decode loop (only __syncthreads); one agent-scope grid
// barrier after weight conversion. Rationale: agent-scope barrier fences
// (buffer_wbl2/buffer_inv) dump the per-XCD L2 every phase -> weights
// re-streamed ~530x. Single-block-per-batch needs no fences at all.
// Decoder GEMMs/attention: bf16 MFMA 16x16x32, fp32 accum/LN/softmax.
// Dual-row-tile GEMMs (wgemm2) keep weight traffic at 6.3MB/layer-step flat.

#define NBLK 16
#define NT 1024
#define Dm 512
#define HIDN 2048
#define TLEN 32
#define NLAY 4
#define RSZ 149504   // floats per batch region

typedef unsigned int uint32;
typedef unsigned short u16;
typedef short bf16x8 __attribute__((ext_vector_type(8)));
typedef float f32x4 __attribute__((ext_vector_type(4)));

struct Params {
  const float* y; const float* start;
  const float *eqw, *eqb, *eow, *eob, *ef1w, *ef1b, *ef2w, *ef2b;
  const float *eln1g, *eln1b, *eln2g, *eln2b, *elnfg, *elnfb;
  const float *dqw, *dqb, *dow, *dob, *dxqw, *dxqb, *dxow, *dxob;
  const float *df1w, *df1b, *df2w, *df2b;
  const float *dln1g, *dln1b, *dln2g, *dln2b, *dln3g, *dln3b, *dlnfg, *dlnfb;
  float* out; float* ws;
};

__device__ __forceinline__ u16 f2b(float x) {
  uint32 u = __float_as_uint(x);
  u += 0x7fffu + ((u >> 16) & 1u);
  return (u16)(u >> 16);
}
__device__ __forceinline__ float dot4f(float4 a, float4 b) {
  return a.x*b.x + a.y*b.y + a.z*b.z + a.w*b.w;
}

struct DecS { u16 P[16][16][32]; u16 u[2][16][2056]; };   // 16KB + 128.5KB
struct EncS { float xs[512]; float as[512]; float h2[512]; float fr[512]; float us[2048]; };
union Smem { DecS d; EncS e; };

__device__ __forceinline__ void wave_ln(float v[8], const float* __restrict__ g,
                                        const float* __restrict__ bt, int cb) {
  float sum = 0.f, sq = 0.f;
#pragma unroll
  for (int q = 0; q < 8; ++q) { sum += v[q]; sq += v[q]*v[q]; }
#pragma unroll
  for (int m = 32; m; m >>= 1) { sum += __shfl_xor(sum, m, 64); sq += __shfl_xor(sq, m, 64); }
  float mean = sum * (1.f/Dm);
  float var  = sq  * (1.f/Dm) - mean*mean;
  float rs = rsqrtf(var + 1e-5f);
#pragma unroll
  for (int q = 0; q < 8; ++q) v[q] = (v[q]-mean)*rs*g[cb+q] + bt[cb+q];
}

// Dual-row-tile 16x64 MFMA GEMM: tiles at rows 0 and 16 of A (if nj>1) share
// one stream of W. A row-major (lda elems), W row-major [N][K].
template<int K>
__device__ __forceinline__ void wgemm2(const u16* __restrict__ A, int lda, int nj,
                                       const u16* __restrict__ W, f32x4 acc[2][4]) {
  const int lane = threadIdx.x & 63;
  const int l15 = lane & 15, kg = lane >> 4;
  const u16* a0 = A + (size_t)l15*lda + kg*8;
  const u16* a1 = a0 + (size_t)(nj > 1 ? 16 : 0)*lda;
#pragma unroll 2
  for (int kc = 0; kc < K/32; ++kc) {
    bf16x8 av0 = *(const bf16x8*)(a0 + kc*32);
    bf16x8 av1 = *(const bf16x8*)(a1 + kc*32);
    const u16* w = W + (size_t)l15*K + kg*8 + kc*32;
#pragma unroll
    for (int cg = 0; cg < 4; ++cg) {
      bf16x8 bv = *(const bf16x8*)(w + (size_t)cg*16*K);
      acc[0][cg] = __builtin_amdgcn_mfma_f32_16x16x32_bf16(av0, bv, acc[0][cg], 0, 0, 0);
      acc[1][cg] = __builtin_amdgcn_mfma_f32_16x16x32_bf16(av1, bv, acc[1][cg], 0, 0, 0);
    }
  }
}

__device__ __forceinline__ float dotn(const float* __restrict__ xn,
                                      const float* __restrict__ w, int n4) {
  const float4* x4 = (const float4*)xn;
  const float4* w4 = (const float4*)w;
  float a = 0.f;
#pragma unroll 8
  for (int k = 0; k < n4; ++k) a += dot4f(x4[k], w4[k]);
  return a;
}

__device__ void convw(const float* __restrict__ s, u16* __restrict__ d, int n,
                      int gtid, int gs) {
  const float2* s2 = (const float2*)s;
  uint32* d2 = (uint32*)d;
  for (int i = gtid; i < n/2; i += gs) {
    float2 v = s2[i];
    d2[i] = (uint32)f2b(v.x) | ((uint32)f2b(v.y) << 16);
  }
}

__global__ __launch_bounds__(NT) void ar_transformer(Params p) {
  __shared__ Smem sm;
  const int bid = blockIdx.x;
  const int b = bid;
  const int t = threadIdx.x;
  const int wv = t >> 6, lane = t & 63, cb = lane * 8;
  const int l15 = lane & 15, kg = lane >> 4;

  // ---- workspace carve ----
  unsigned* cnt = (unsigned*)p.ws;
  u16* wq16 = (u16*)(p.ws + 256);
  u16* wo16 = wq16 + (size_t)NLAY*1536*512;
  u16* w116 = wo16 + (size_t)NLAY*512*512;
  u16* w216 = w116 + (size_t)NLAY*2048*512;
  float* bat0 = (float*)(w216 + (size_t)NLAY*512*2048);

  float* bb   = bat0 + (size_t)b * RSZ;
  float* pe   = bb;             // 16384
  float* h0f  = bb + 16384;     // 16384
  float* hf   = bb + 32768;     // 16384
  float* h2f  = bb + 49152;     // 16384
  float* ofb  = bb + 65536;     // 16384 (32x512 f32, reused by outproj & ffn2)
  float* crossE = bb + 81920;   // 2048  (4 layers x 512)
  u16* h0b  = (u16*)(bb + 83968);
  u16* hb   = h0b + 16384;
  u16* h2b  = hb + 16384;
  u16* qkvb = h2b + 16384;      // 32x1536
  u16* vt   = qkvb + 49152;     // 512x32 (V transposed)
  u16* obb  = vt + 16384;       // 32x512 attn out

  const int gtid = bid*NT + t, gs = NBLK*NT;

  // ---------- init ----------
  convw(p.dqw,  wq16, NLAY*1536*512, gtid, gs);
  convw(p.dow,  wo16, NLAY*512*512,  gtid, gs);
  convw(p.df1w, w116, NLAY*2048*512, gtid, gs);
  convw(p.df2w, w216, NLAY*512*2048, gtid, gs);
  for (int i = t; i < TLEN*Dm; i += NT) {         // per-batch pe copy
    int tt = i >> 9, d = i & (Dm-1);
    int half = d >> 1;
    float ang = (float)tt * expf(-(float)(2*half) * (9.210340371976184f/512.0f));
    pe[i] = (d & 1) ? cosf(ang) : sinf(ang);
  }
  if (t < 512) {                                   // h0 row 0
    float v0 = p.start[t] + ((t & 1) ? 1.0f : 0.0f);
    h0f[t] = v0; h0b[t] = f2b(v0);
  }
  // one-time grid barrier: weights converted by all blocks, read by all
  __syncthreads();
  if (t == 0) {
    __hip_atomic_fetch_add(cnt, 1u, __ATOMIC_RELEASE, __HIP_MEMORY_SCOPE_AGENT);
    while (__hip_atomic_load(cnt, __ATOMIC_RELAXED, __HIP_MEMORY_SCOPE_AGENT) < (unsigned)NBLK)
      __builtin_amdgcn_s_sleep(2);
    (void)__hip_atomic_load(cnt, __ATOMIC_ACQUIRE, __HIP_MEMORY_SCOPE_AGENT);
  }
  __syncthreads();

  // ---------- encoder (fp32, in-block; S=1 so attn out == V) ----------
  for (int l = 0; l < NLAY; ++l) {
    if (l == 0) {
      if (t < 512) sm.e.xs[t] = p.y[(size_t)b*512 + t] + ((t & 1) ? 1.0f : 0.0f);
    } else if (wv == 0) {
      float v[8];
#pragma unroll
      for (int q = 0; q < 8; ++q) v[q] = sm.e.h2[cb+q] + sm.e.fr[cb+q];
      wave_ln(v, p.eln2g + (l-1)*Dm, p.eln2b + (l-1)*Dm, cb);
#pragma unroll
      for (int q = 0; q < 8; ++q) sm.e.xs[cb+q] = v[q];
    }
    __syncthreads();
    if (t < 512)
      sm.e.as[t] = dotn(sm.e.xs, p.eqw + ((size_t)l*1536 + 1024 + t)*512, 128)
                   + p.eqb[l*1536 + 1024 + t];
    __syncthreads();
    if (t < 512)
      sm.e.fr[t] = dotn(sm.e.as, p.eow + ((size_t)l*512 + t)*512, 128) + p.eob[l*512 + t];
    __syncthreads();
    if (wv == 0) {
      float v[8];
#pragma unroll
      for (int q = 0; q < 8; ++q) v[q] = sm.e.xs[cb+q] + sm.e.fr[cb+q];
      wave_ln(v, p.eln1g + l*Dm, p.eln1b + l*Dm, cb);
#pragma unroll
      for (int q = 0; q < 8; ++q) sm.e.h2[cb+q] = v[q];
    }
    __syncthreads();
    for (int c = t; c < 2048; c += NT) {
      float u = dotn(sm.e.h2, p.ef1w + ((size_t)l*2048 + c)*512, 128) + p.ef1b[l*2048 + c];
      sm.e.us[c] = 0.5f*u*(1.0f + erff(u*0.70710678118654752f));
    }
    __syncthreads();
    if (t < 512)
      sm.e.fr[t] = dotn(sm.e.us, p.ef2w + ((size_t)l*512 + t)*2048, 512) + p.ef2b[l*512 + t];
    __syncthreads();
  }
  if (wv == 0) {   // mem = LNf(LN2(h2 + fr))
    float v[8];
#pragma unroll
    for (int q = 0; q < 8; ++q) v[q] = sm.e.h2[cb+q] + sm.e.fr[cb+q];
    wave_ln(v, p.eln2g + 3*Dm, p.eln2b + 3*Dm, cb);
    wave_ln(v, p.elnfg, p.elnfb, cb);
#pragma unroll
    for (int q = 0; q < 8; ++q) sm.e.xs[cb+q] = v[q];
  }
  __syncthreads();
  for (int c = t; c < 2048; c += NT) {   // cross V per layer
    int lc = c >> 9, cc = c & 511;
    sm.e.us[c] = dotn(sm.e.xs, p.dxqw + ((size_t)lc*1536 + 1024 + cc)*512, 128)
                 + p.dxqb[lc*1536 + 1024 + cc];
  }
  __syncthreads();
  for (int c = t; c < 2048; c += NT) {   // cross = vx @ Wxo^T + bxo
    int lc = c >> 9, cc = c & 511;
    crossE[c] = dotn(sm.e.us + lc*512, p.dxow + ((size_t)lc*512 + cc)*512, 128)
                + p.dxob[lc*512 + cc];
  }
  __syncthreads();

  // ---------- autoregressive decode (entirely in-block) ----------
  for (int st = 0; st < TLEN; ++st) {
    const int s = st + 1;
    const int JT = (s + 15) >> 4;
    const int jtL = (s - 1) >> 4;
    for (int l = 0; l < NLAY; ++l) {
      const int RT0 = (l == NLAY-1) ? jtL : 0;
      const int RN  = (l == NLAY-1) ? 1 : JT;
      const u16* Asrc = (l == 0) ? h0b : hb;

      // ---- a) QKV (dual row-tile per W stream); V transposed into vt ----
      for (int it = wv; it < 24; it += 16) {
        int c0 = it*64;
        f32x4 acc[2][4];
#pragma unroll
        for (int a2 = 0; a2 < 2; ++a2)
#pragma unroll
          for (int cg = 0; cg < 4; ++cg) acc[a2][cg] = (f32x4){0.f,0.f,0.f,0.f};
        wgemm2<512>(Asrc, 512, JT, wq16 + ((size_t)l*1536 + c0)*512, acc);
        for (int jl = 0; jl < JT; ++jl)
#pragma unroll
          for (int cg = 0; cg < 4; ++cg) {
            int col = c0 + cg*16 + l15;
            float bias = p.dqb[l*1536 + col];
#pragma unroll
            for (int r = 0; r < 4; ++r) {
              int j = jl*16 + kg*4 + r;
              if (j < s) {
                float v = acc[jl][cg][r] + bias;
                if (col < 512)       qkvb[(size_t)j*1536 + col] = f2b(v * 0.125f);
                else if (col < 1024) qkvb[(size_t)j*1536 + col] = f2b(v);
                else                 vt[(size_t)(col-1024)*32 + j] = f2b(v);
              }
            }
          }
      }
      __syncthreads();

      // ---- b) attention: wave = (head, row-tile) ----
      {
        bool act = wv < 8*RN;
        int h = wv & 7, jt = RT0 + (wv >> 3);
        if (act) {
          f32x4 sc[2] = {};
          const u16* qA = qkvb + (size_t)(jt*16 + l15)*1536 + h*64 + kg*8;
          const u16* kB = qkvb + 512 + h*64 + kg*8;
#pragma unroll
          for (int ks = 0; ks < 2; ++ks) {
            bf16x8 av = *(const bf16x8*)(qA + ks*32);
#pragma unroll
            for (int cg = 0; cg < 2; ++cg) {
              bf16x8 bv = *(const bf16x8*)(kB + (size_t)(cg*16 + l15)*1536 + ks*32);
              sc[cg] = __builtin_amdgcn_mfma_f32_16x16x32_bf16(av, bv, sc[cg], 0, 0, 0);
            }
          }
#pragma unroll
          for (int r = 0; r < 4; ++r) {
            float v0 = (l15      < s) ? sc[0][r] : -3.0e38f;
            float v1 = (l15 + 16 < s) ? sc[1][r] : -3.0e38f;
            float mx = fmaxf(v0, v1);
#pragma unroll
            for (int mk = 1; mk < 16; mk <<= 1) mx = fmaxf(mx, __shfl_xor(mx, mk, 64));
            float e0 = expf(v0 - mx), e1 = expf(v1 - mx);
            float sum = e0 + e1;
#pragma unroll
            for (int mk = 1; mk < 16; mk <<= 1) sum += __shfl_xor(sum, mk, 64);
            float inv = 1.0f / sum;
            int row = kg*4 + r;
            sm.d.P[wv][row][l15]      = f2b(e0 * inv);
            sm.d.P[wv][row][16 + l15] = f2b(e1 * inv);
          }
          // P @ V (same wave; compiler orders LDS write->read)
          f32x4 ov[4] = {};
          bf16x8 pa = *(const bf16x8*)&sm.d.P[wv][l15][kg*8];
#pragma unroll
          for (int cg = 0; cg < 4; ++cg) {
            bf16x8 bv = *(const bf16x8*)(vt + (size_t)(h*64 + cg*16 + l15)*32 + kg*8);
            ov[cg] = __builtin_amdgcn_mfma_f32_16x16x32_bf16(pa, bv, ov[cg], 0, 0, 0);
          }
#pragma unroll
          for (int cg = 0; cg < 4; ++cg)
#pragma unroll
            for (int r = 0; r < 4; ++r)
              obb[(size_t)(jt*16 + kg*4 + r)*512 + h*64 + cg*16 + l15] = f2b(ov[cg][r]);
        }
      }
      __syncthreads();

      // ---- c) out-proj -> ofb ----
      for (int it = wv; it < 8*RN; it += 16) {
        int c0 = (it & 7)*64, jt = RT0 + (it >> 3);
        f32x4 acc[2][4];
#pragma unroll
        for (int a2 = 0; a2 < 2; ++a2)
#pragma unroll
          for (int cg = 0; cg < 4; ++cg) acc[a2][cg] = (f32x4){0.f,0.f,0.f,0.f};
        wgemm2<512>(obb + (size_t)jt*16*512, 512, 1, wo16 + ((size_t)l*512 + c0)*512, acc);
#pragma unroll
        for (int cg = 0; cg < 4; ++cg) {
          int col = c0 + cg*16 + l15;
          float bias = p.dob[l*512 + col];
#pragma unroll
          for (int r = 0; r < 4; ++r)
            ofb[(size_t)(jt*16 + kg*4 + r)*512 + col] = acc[0][cg][r] + bias;
        }
      }
      __syncthreads();

      // ---- d) LN1 + cross + LN2 -> h2 ----
      {
        const float* xin = (l == 0) ? h0f : hf;
        for (int r = wv; r < RN*16; r += 16) {
          int j = RT0*16 + r;
          float v[8];
#pragma unroll
          for (int q = 0; q < 8; ++q) v[q] = xin[(size_t)j*512 + cb+q] + ofb[(size_t)j*512 + cb+q];
          wave_ln(v, p.dln1g + l*512, p.dln1b + l*512, cb);
#pragma unroll
          for (int q = 0; q < 8; ++q) v[q] += crossE[l*512 + cb+q];
          wave_ln(v, p.dln2g + l*512, p.dln2b + l*512, cb);
          if (j < s) {
#pragma unroll
            for (int q = 0; q < 8; ++q) {
              h2f[(size_t)j*512 + cb+q] = v[q];
              h2b[(size_t)j*512 + cb+q] = f2b(v[q]);
            }
          }
        }
      }
      __syncthreads();

      // ---- e) FFN1 -> u (LDS), dual tile per W stream ----
      for (int it = wv; it < 32; it += 16) {
        int c0 = it*64;
        f32x4 acc[2][4];
#pragma unroll
        for (int a2 = 0; a2 < 2; ++a2)
#pragma unroll
          for (int cg = 0; cg < 4; ++cg) acc[a2][cg] = (f32x4){0.f,0.f,0.f,0.f};
        wgemm2<512>(h2b + (size_t)RT0*16*512, 512, RN, w116 + ((size_t)l*2048 + c0)*512, acc);
        for (int jl = 0; jl < RN; ++jl)
#pragma unroll
          for (int cg = 0; cg < 4; ++cg) {
            int col = c0 + cg*16 + l15;
            float bias = p.df1b[l*2048 + col];
#pragma unroll
            for (int r = 0; r < 4; ++r) {
              float u = acc[jl][cg][r] + bias;
              sm.d.u[jl][kg*4 + r][col] = f2b(0.5f*u*(1.0f + erff(u*0.70710678118654752f)));
            }
          }
      }
      __syncthreads();
      // ---- FFN2 (u from LDS) -> ofb ----
      for (int it = wv; it < 8; it += 16) {
        int c0 = it*64;
        f32x4 acc[2][4];
#pragma unroll
        for (int a2 = 0; a2 < 2; ++a2)
#pragma unroll
          for (int cg = 0; cg < 4; ++cg) acc[a2][cg] = (f32x4){0.f,0.f,0.f,0.f};
        wgemm2<2048>((const u16*)&sm.d.u[0][0][0], 2056, RN, w216 + ((size_t)l*512 + c0)*2048, acc);
        for (int jl = 0; jl < RN; ++jl)
#pragma unroll
          for (int cg = 0; cg < 4; ++cg) {
            int col = c0 + cg*16 + l15;
            float bias = p.df2b[l*512 + col];
#pragma unroll
            for (int r = 0; r < 4; ++r)
              ofb[(size_t)(RT0*16 + jl*16 + kg*4 + r)*512 + col] = acc[jl][cg][r] + bias;
          }
      }
      __syncthreads();

      // ---- f) LN3 (+ final LN, output, next h0) -> h ----
      for (int r = wv; r < RN*16; r += 16) {
        int j = RT0*16 + r;
        float v[8];
#pragma unroll
        for (int q = 0; q < 8; ++q) v[q] = h2f[(size_t)j*512 + cb+q] + ofb[(size_t)j*512 + cb+q];
        wave_ln(v, p.dln3g + l*512, p.dln3b + l*512, cb);
        if (j < s) {
#pragma unroll
          for (int q = 0; q < 8; ++q) {
            hf[(size_t)j*512 + cb+q] = v[q];
            hb[(size_t)j*512 + cb+q] = f2b(v[q]);
          }
        }
        if (l == NLAY-1 && j == s-1) {
          wave_ln(v, p.dlnfg, p.dlnfb, cb);
#pragma unroll
          for (int q = 0; q < 8; ++q) {
            float ov = v[q];
            p.out[(size_t)(b*TLEN + st)*512 + cb+q] = ov;
            if (st + 1 < TLEN) {
              float nh = ov + pe[(size_t)(st+1)*512 + cb+q];
              h0f[(size_t)(st+1)*512 + cb+q] = nh;
              h0b[(size_t)(st+1)*512 + cb+q] = f2b(nh);
            }
          }
        }
      }
      __syncthreads();
    }
  }
}

extern "C" void kernel_launch(void* const* d_in, const int* in_sizes, int n_in,
                              void* d_out, int out_size, void* d_ws, size_t ws_size,
                              hipStream_t stream) {
  Params P;
  P.y     = (const float*)d_in[0];
  P.start = (const float*)d_in[1];
  // d_in[2] = target_length (fixed 32)
  P.eqw  = (const float*)d_in[3];  P.eqb  = (const float*)d_in[4];
  P.eow  = (const float*)d_in[5];  P.eob  = (const float*)d_in[6];
  P.ef1w = (const float*)d_in[7];  P.ef1b = (const float*)d_in[8];
  P.ef2w = (const float*)d_in[9];  P.ef2b = (const float*)d_in[10];
  P.eln1g = (const float*)d_in[11]; P.eln1b = (const float*)d_in[12];
  P.eln2g = (const float*)d_in[13]; P.eln2b = (const float*)d_in[14];
  P.elnfg = (const float*)d_in[15]; P.elnfb = (const float*)d_in[16];
  P.dqw  = (const float*)d_in[17]; P.dqb  = (const float*)d_in[18];
  P.dow  = (const float*)d_in[19]; P.dob  = (const float*)d_in[20];
  P.dxqw = (const float*)d_in[21]; P.dxqb = (const float*)d_in[22];
  P.dxow = (const float*)d_in[23]; P.dxob = (const float*)d_in[24];
  P.df1w = (const float*)d_in[25]; P.df1b = (const float*)d_in[26];
  P.df2w = (const float*)d_in[27]; P.df2b = (const float*)d_in[28];
  P.dln1g = (const float*)d_in[29]; P.dln1b = (const float*)d_in[30];
  P.dln2g = (const float*)d_in[31]; P.dln2b = (const float*)d_in[32];
  P.dln3g = (const float*)d_in[33]; P.dln3b = (const float*)d_in[34];
  P.dlnfg = (const float*)d_in[35]; P.dlnfb = (const float*)d_in[36];
  P.out = (float*)d_out;
  P.ws  = (float*)d_ws;
  hipMemsetAsync(d_ws, 0, 1024, stream);   // zero init-barrier counter
  hipLaunchKernelGGL(ar_transformer, dim3(NBLK), dim3(NT), 0, stream, P);
}

// Round 6
// 35910.779 us; speedup vs baseline: 1.0544x; 1.0544x over previous
//
#include <hip/hip_runtime.h>
#include <math.h>

// AutoregTransformer D=512 HID=2048 NH=8 L=4 T=32 B=16, fp32 in/out.
// R5 (resubmit; prior round hit GPU-broker timeout, never ran):
// 16 groups (batch) x 8 blocks x 512 thr. FENCE-FREE sync:
//  - barrier = RELEASE fetch_add (buffer_wbl2, cheap) + RELAXED spin, NO acquire
//    (acquire's buffer_inv was dumping L2 -> 6MB weight refetch per phase in R2-R4).
//  - all cross-block activations exchanged via RELAXED agent-scope 4/8B atomics
//    (sc1 -> L3 coherence point), so weights stay valid in per-XCD L2.
// Encoder + cross-attn precompute: fully block-local (redundant per block, 0 barriers).
// Decoder: 4 phases/layer (QKV | ATN+OUT+LN1+cross+LN2 | FFN1 | FFN2) + FIN/step.
// LN3 recomputed on the fly by consumers (no h buffer). bf16 MFMA, fp32 LN/softmax.

#define NB 128
#define NT 512
#define GM 8
#define TLEN 32
#define NLAY 4
#define GSZ 122880   // floats per group region

typedef unsigned int u32;
typedef unsigned long long u64;
typedef unsigned short u16;
typedef short bf16x8 __attribute__((ext_vector_type(8)));
typedef float f32x4 __attribute__((ext_vector_type(4)));

struct Params {
  const float* y; const float* start;
  const float *eqw, *eqb, *eow, *eob, *ef1w, *ef1b, *ef2w, *ef2b;
  const float *eln1g, *eln1b, *eln2g, *eln2b, *elnfg, *elnfb;
  const float *dqw, *dqb, *dow, *dob, *dxqw, *dxqb, *dxow, *dxob;
  const float *df1w, *df1b, *df2w, *df2b;
  const float *dln1g, *dln1b, *dln2g, *dln2b, *dln3g, *dln3b, *dlnfg, *dlnfb;
  float* out; float* ws;
};

union U8 { u64 u; u32 w[2]; u16 h[4]; float f[2]; };

__device__ __forceinline__ u16 f2b(float x) {
  u32 u = __float_as_uint(x);
  u += 0x7fffu + ((u >> 16) & 1u);
  return (u16)(u >> 16);
}
__device__ __forceinline__ float dot4f(float4 a, float4 b) {
  return a.x*b.x + a.y*b.y + a.z*b.z + a.w*b.w;
}
__device__ __forceinline__ void ast4(u16* p, u32 v) {
  __hip_atomic_store((u32*)p, v, __ATOMIC_RELAXED, __HIP_MEMORY_SCOPE_AGENT);
}
__device__ __forceinline__ void ast8(void* p, u64 v) {
  __hip_atomic_store((u64*)p, v, __ATOMIC_RELAXED, __HIP_MEMORY_SCOPE_AGENT);
}
__device__ __forceinline__ u64 ald8(const void* p) {
  return __hip_atomic_load((const u64*)p, __ATOMIC_RELAXED, __HIP_MEMORY_SCOPE_AGENT);
}

struct QS  { u16 A[32][520]; };
struct AtnS{ u16 Qs[16][520]; u16 Ks[32][520]; u16 Vt[512][40];
             u16 P[8][16][32]; u16 Ob[16][520]; float Of[16][516]; };
struct F2S { u16 A[32][2056]; };
struct EncS{ float xs[512]; float as[512]; float h2[512]; float fr[512]; float us[2048]; };
union Smem { QS q; AtnS a; F2S f2; EncS e; };   // 148,736 B

__device__ __forceinline__ void wave_ln(float v[8], const float* __restrict__ g,
                                        const float* __restrict__ bt, int cb) {
  float sum = 0.f, sq = 0.f;
#pragma unroll
  for (int q = 0; q < 8; ++q) { sum += v[q]; sq += v[q]*v[q]; }
#pragma unroll
  for (int mk = 32; mk; mk >>= 1) { sum += __shfl_xor(sum, mk, 64); sq += __shfl_xor(sq, mk, 64); }
  float mean = sum * (1.f/512.f);
  float var  = sq  * (1.f/512.f) - mean*mean;
  float rs = rsqrtf(var + 1e-5f);
#pragma unroll
  for (int q = 0; q < 8; ++q) v[q] = (v[q]-mean)*rs*g[cb+q] + bt[cb+q];
}

// Dual-row-tile 16x64 MFMA GEMM. A row-major (lda elems, rows 0..15 and 16..31
// if nj>1), W row-major [N][K] pre-offset to col base.
template<int K>
__device__ __forceinline__ void wgemm2(const u16* __restrict__ A, int lda, int nj,
                                       const u16* __restrict__ W, f32x4 acc[2][4]) {
  const int lane = threadIdx.x & 63;
  const int l15 = lane & 15, kg = lane >> 4;
  const u16* a0 = A + (size_t)l15*lda + kg*8;
  const u16* a1 = a0 + (size_t)(nj > 1 ? 16 : 0)*lda;
#pragma unroll 2
  for (int kc = 0; kc < K/32; ++kc) {
    bf16x8 av0 = *(const bf16x8*)(a0 + kc*32);
    bf16x8 av1 = *(const bf16x8*)(a1 + kc*32);
    const u16* w = W + (size_t)l15*K + kg*8 + kc*32;
#pragma unroll
    for (int cg = 0; cg < 4; ++cg) {
      bf16x8 bv = *(const bf16x8*)(w + (size_t)cg*16*K);
      acc[0][cg] = __builtin_amdgcn_mfma_f32_16x16x32_bf16(av0, bv, acc[0][cg], 0, 0, 0);
      acc[1][cg] = __builtin_amdgcn_mfma_f32_16x16x32_bf16(av1, bv, acc[1][cg], 0, 0, 0);
    }
  }
}

__device__ __forceinline__ float dotn(const float* __restrict__ xn,
                                      const float* __restrict__ w, int n4) {
  const float4* x4 = (const float4*)xn;
  const float4* w4 = (const float4*)w;
  float a = 0.f;
#pragma unroll 8
  for (int k = 0; k < n4; ++k) a += dot4f(x4[k], w4[k]);
  return a;
}

__device__ void convw(const float* __restrict__ s, u16* __restrict__ d, int n,
                      int gtid, int gs) {
  const float2* s2 = (const float2*)s;
  u32* d2 = (u32*)d;
  for (int i = gtid; i < n/2; i += gs) {
    float2 v = s2[i];
    d2[i] = (u32)f2b(v.x) | ((u32)f2b(v.y) << 16);
  }
}

// fence-free group barrier: release add (wbl2 only) + relaxed spin, NO acquire.
#define BAR(cp, n, ep) do {                                                       \
    __syncthreads();                                                              \
    if (t == 0) {                                                                 \
      __hip_atomic_fetch_add((cp), 1u, __ATOMIC_RELEASE, __HIP_MEMORY_SCOPE_AGENT);\
      ++(ep);                                                                     \
      unsigned tg_ = (ep) * (unsigned)(n);                                        \
      while (__hip_atomic_load((cp), __ATOMIC_RELAXED, __HIP_MEMORY_SCOPE_AGENT) < tg_) \
        __builtin_amdgcn_s_sleep(2);                                              \
    }                                                                             \
    __syncthreads();                                                              \
  } while (0)

__global__ __launch_bounds__(NT) void ar_transformer(Params p) {
  __shared__ Smem sm;
  const int bid = blockIdx.x;
  const int t = threadIdx.x;
  const int g = bid & 15;        // group == batch
  const int m = bid >> 4;        // member 0..7
  const int b = g;
  const int wv = t >> 6, lane = t & 63, cb = lane * 8;
  const int l15 = lane & 15, kg = lane >> 4;
  unsigned epG = 0;

  // ---- ws carve ----
  u32* cntI = (u32*)p.ws;
  u32* cntG = (u32*)p.ws + 16 + g*16;
  float* crossB = p.ws + 1024 + (size_t)bid*2048;        // block-private
  float* grp0   = p.ws + 1024 + 128*2048;
  float* gb = grp0 + (size_t)g * GSZ;
  float* h0f = gb;                 // [32][512] f32 (tgt+pe rows)
  float* h2f = gb + 16384;         // [32][512] f32
  float* ofb = gb + 32768;         // [32][512] f32 (outproj/ffn2 out)
  u16* h0b  = (u16*)(gb + 49152);  // [32][512] bf16
  u16* h2b  = h0b + 16384;         // [32][512] bf16
  u16* qkvb = h2b + 16384;         // [32][1024] bf16 (q 0..511 | k 512..1023)
  u16* vtw  = qkvb + 32768;        // [512][32] bf16 (V transposed)
  u16* ubuf = vtw + 16384;         // [32][2048] bf16
  u16* wq16 = (u16*)(grp0 + (size_t)16*GSZ);
  u16* wo16 = wq16 + (size_t)NLAY*1536*512;
  u16* w116 = wo16 + (size_t)NLAY*512*512;
  u16* w216 = w116 + (size_t)NLAY*2048*512;

  const int gtid = bid*NT + t, gs = NB*NT;

  // ---------- init: weight conversion (strided, all blocks) ----------
  convw(p.dqw,  wq16, NLAY*1536*512, gtid, gs);
  convw(p.dow,  wo16, NLAY*512*512,  gtid, gs);
  convw(p.df1w, w116, NLAY*2048*512, gtid, gs);
  convw(p.df2w, w216, NLAY*512*2048, gtid, gs);

  // ---------- encoder: fully block-local (redundant per block) ----------
  for (int l = 0; l < NLAY; ++l) {
    if (l == 0) {
      if (t < 512) sm.e.xs[t] = p.y[(size_t)b*512 + t] + ((t & 1) ? 1.0f : 0.0f);
    } else if (wv == 0) {
      float v[8];
#pragma unroll
      for (int q = 0; q < 8; ++q) v[q] = sm.e.h2[cb+q] + sm.e.fr[cb+q];
      wave_ln(v, p.eln2g + (l-1)*512, p.eln2b + (l-1)*512, cb);
#pragma unroll
      for (int q = 0; q < 8; ++q) sm.e.xs[cb+q] = v[q];
    }
    __syncthreads();
    if (t < 512)
      sm.e.as[t] = dotn(sm.e.xs, p.eqw + ((size_t)l*1536 + 1024 + t)*512, 128)
                   + p.eqb[l*1536 + 1024 + t];
    __syncthreads();
    if (t < 512)
      sm.e.fr[t] = dotn(sm.e.as, p.eow + ((size_t)l*512 + t)*512, 128) + p.eob[l*512 + t];
    __syncthreads();
    if (wv == 0) {
      float v[8];
#pragma unroll
      for (int q = 0; q < 8; ++q) v[q] = sm.e.xs[cb+q] + sm.e.fr[cb+q];
      wave_ln(v, p.eln1g + l*512, p.eln1b + l*512, cb);
#pragma unroll
      for (int q = 0; q < 8; ++q) sm.e.h2[cb+q] = v[q];
    }
    __syncthreads();
    for (int c = t; c < 2048; c += NT) {
      float u = dotn(sm.e.h2, p.ef1w + ((size_t)l*2048 + c)*512, 128) + p.ef1b[l*2048 + c];
      sm.e.us[c] = 0.5f*u*(1.0f + erff(u*0.70710678118654752f));
    }
    __syncthreads();
    if (t < 512)
      sm.e.fr[t] = dotn(sm.e.us, p.ef2w + ((size_t)l*512 + t)*2048, 512) + p.ef2b[l*512 + t];
    __syncthreads();
  }
  if (wv == 0) {   // mem = LNf(LN2(h2 + fr))
    float v[8];
#pragma unroll
    for (int q = 0; q < 8; ++q) v[q] = sm.e.h2[cb+q] + sm.e.fr[cb+q];
    wave_ln(v, p.eln2g + 3*512, p.eln2b + 3*512, cb);
    wave_ln(v, p.elnfg, p.elnfb, cb);
#pragma unroll
    for (int q = 0; q < 8; ++q) sm.e.xs[cb+q] = v[q];
  }
  __syncthreads();
  for (int c = t; c < 2048; c += NT) {      // cross-V per layer
    int lc = c >> 9, cc = c & 511;
    sm.e.us[c] = dotn(sm.e.xs, p.dxqw + ((size_t)lc*1536 + 1024 + cc)*512, 128)
                 + p.dxqb[lc*1536 + 1024 + cc];
  }
  __syncthreads();
  for (int c = t; c < 2048; c += NT) {      // crossB = vx @ Wxo^T + bxo (block-private)
    int lc = c >> 9, cc = c & 511;
    crossB[c] = dotn(sm.e.us + lc*512, p.dxow + ((size_t)lc*512 + cc)*512, 128)
                + p.dxob[lc*512 + cc];
  }
  // h0 row 0 (member 0 publishes)
  if (m == 0) {
    if (t < 256) {
      int c = t*2;
      U8 x; x.f[0] = p.start[c]   + ((c & 1) ? 1.0f : 0.0f);
      x.f[1] = p.start[c+1] + (((c+1) & 1) ? 1.0f : 0.0f);
      ast8(&h0f[c], x.u);
    }
    if (t < 128) {
      int c = t*4;
      U8 pk;
#pragma unroll
      for (int q2 = 0; q2 < 4; ++q2)
        pk.h[q2] = f2b(p.start[c+q2] + (((c+q2) & 1) ? 1.0f : 0.0f));
      ast8(&h0b[c], pk.u);
    }
  }
  // ---- single init grid barrier (release only) ----
  __syncthreads();
  if (t == 0) {
    __hip_atomic_fetch_add(cntI, 1u, __ATOMIC_RELEASE, __HIP_MEMORY_SCOPE_AGENT);
    while (__hip_atomic_load(cntI, __ATOMIC_RELAXED, __HIP_MEMORY_SCOPE_AGENT) < (unsigned)NB)
      __builtin_amdgcn_s_sleep(2);
  }
  __syncthreads();

  // ---------- autoregressive decode ----------
  for (int st = 0; st < TLEN; ++st) {
    const int s = st + 1;
    const int JT = (s + 15) >> 4;
    const int jtL = (s - 1) >> 4;
    for (int l = 0; l < NLAY; ++l) {
      // ======== Q: stage LN3(h2f+ofb)/h0 -> LDS; QKV GEMM -> qkvb/vtw ========
      {
        const int nr = JT*16;
        for (int j = wv; j < nr; j += 8) {
          if (l == 0) {
            u64 a0 = ald8(h0b + j*512 + cb);
            u64 a1 = ald8(h0b + j*512 + cb + 4);
            *(u64*)&sm.q.A[j][cb] = a0;
            *(u64*)&sm.q.A[j][cb+4] = a1;
          } else {
            float v[8];
#pragma unroll
            for (int qq = 0; qq < 4; ++qq) {
              U8 x{ald8(h2f + j*512 + cb + qq*2)};
              U8 o{ald8(ofb + j*512 + cb + qq*2)};
              v[qq*2] = x.f[0]+o.f[0]; v[qq*2+1] = x.f[1]+o.f[1];
            }
            wave_ln(v, p.dln3g + (l-1)*512, p.dln3b + (l-1)*512, cb);
            U8 o0, o1;
#pragma unroll
            for (int qq = 0; qq < 4; ++qq) { o0.h[qq] = f2b(v[qq]); o1.h[qq] = f2b(v[4+qq]); }
            *(u64*)&sm.q.A[j][cb] = o0.u; *(u64*)&sm.q.A[j][cb+4] = o1.u;
          }
        }
        __syncthreads();
        const u16* wql = wq16 + (size_t)l*1536*512;
        for (int k3 = 0; k3 < 3; ++k3) {
          int c0 = (m + k3*8)*64;
          f32x4 acc[2][4];
#pragma unroll
          for (int a2 = 0; a2 < 2; ++a2)
#pragma unroll
            for (int cg = 0; cg < 4; ++cg) acc[a2][cg] = (f32x4){0.f,0.f,0.f,0.f};
          wgemm2<512>(&sm.q.A[0][0], 520, JT, wql + (size_t)c0*512, acc);
          for (int jl = 0; jl < JT; ++jl)
#pragma unroll
            for (int cg = 0; cg < 4; ++cg) {
              int col = c0 + cg*16 + l15;
              float bias = p.dqb[l*1536 + col];
              if (col < 1024) {
#pragma unroll
                for (int r = 0; r < 4; ++r) {
                  int j = jl*16 + kg*4 + r;
                  float v = acc[jl][cg][r] + bias;
                  if (col < 512) v *= 0.125f;
                  u16 bv = f2b(v);
                  u32 ov = (u32)__shfl_xor((int)(u32)bv, 1);
                  if (!(l15 & 1)) ast4(&qkvb[j*1024 + col], (u32)bv | (ov << 16));
                }
              } else {
                int d = col - 1024;
                U8 pk;
#pragma unroll
                for (int r = 0; r < 4; ++r) pk.h[r] = f2b(acc[jl][cg][r] + bias);
                ast8(&vtw[d*32 + jl*16 + kg*4], pk.u);
              }
            }
        }
      }
      BAR(cntG, GM, epG);
      // ======== A: attention + out-proj + LN1 + cross + LN2 -> h2 ========
      {
        bool act; int jt;
        if (l == NLAY-1) { act = (m == 0); jt = jtL; } else { act = (m < JT); jt = m; }
        if (act) {
          for (int i = t; i < 16*32; i += NT) {
            int j = i >> 5, cc = (i & 31)*16;
#pragma unroll
            for (int k = 0; k < 4; ++k)
              *(u64*)&sm.a.Qs[j][cc + k*4] = ald8(qkvb + (jt*16 + j)*1024 + cc + k*4);
          }
          for (int i = t; i < 32*32; i += NT) {
            int j = i >> 5, cc = (i & 31)*16;
#pragma unroll
            for (int k = 0; k < 4; ++k)
              *(u64*)&sm.a.Ks[j][cc + k*4] = ald8(qkvb + j*1024 + 512 + cc + k*4);
          }
          {
            int d = t;
#pragma unroll
            for (int k = 0; k < 8; ++k)
              *(u64*)&sm.a.Vt[d][k*4] = ald8(vtw + d*32 + k*4);
          }
          __syncthreads();
          const int h = wv;
          f32x4 sc[2] = {};
#pragma unroll
          for (int ks = 0; ks < 2; ++ks) {
            bf16x8 av = *(const bf16x8*)&sm.a.Qs[l15][h*64 + kg*8 + ks*32];
#pragma unroll
            for (int cg = 0; cg < 2; ++cg) {
              bf16x8 bv = *(const bf16x8*)&sm.a.Ks[cg*16 + l15][h*64 + kg*8 + ks*32];
              sc[cg] = __builtin_amdgcn_mfma_f32_16x16x32_bf16(av, bv, sc[cg], 0, 0, 0);
            }
          }
#pragma unroll
          for (int r = 0; r < 4; ++r) {
            float v0 = (l15      < s) ? sc[0][r] : -3.0e38f;
            float v1 = (l15 + 16 < s) ? sc[1][r] : -3.0e38f;
            float mx = fmaxf(v0, v1);
#pragma unroll
            for (int mk = 1; mk < 16; mk <<= 1) mx = fmaxf(mx, __shfl_xor(mx, mk, 64));
            float e0 = expf(v0 - mx), e1 = expf(v1 - mx);
            float sum = e0 + e1;
#pragma unroll
            for (int mk = 1; mk < 16; mk <<= 1) sum += __shfl_xor(sum, mk, 64);
            float inv = 1.0f / sum;
            int row = kg*4 + r;
            sm.a.P[h][row][l15]      = f2b(e0 * inv);
            sm.a.P[h][row][16 + l15] = f2b(e1 * inv);
          }
          f32x4 ov[4] = {};
          bf16x8 pa = *(const bf16x8*)&sm.a.P[h][l15][kg*8];
#pragma unroll
          for (int cg = 0; cg < 4; ++cg) {
            bf16x8 bv = *(const bf16x8*)&sm.a.Vt[h*64 + cg*16 + l15][kg*8];
            ov[cg] = __builtin_amdgcn_mfma_f32_16x16x32_bf16(pa, bv, ov[cg], 0, 0, 0);
          }
#pragma unroll
          for (int cg = 0; cg < 4; ++cg)
#pragma unroll
            for (int r = 0; r < 4; ++r)
              sm.a.Ob[kg*4 + r][h*64 + cg*16 + l15] = f2b(ov[cg][r]);
          __syncthreads();
          f32x4 oc[4] = {};
          int c0 = wv*64;
          const u16* wB = wo16 + ((size_t)l*512 + c0 + l15)*512 + kg*8;
#pragma unroll 4
          for (int ks = 0; ks < 16; ++ks) {
            bf16x8 av = *(const bf16x8*)&sm.a.Ob[l15][kg*8 + ks*32];
#pragma unroll
            for (int cg = 0; cg < 4; ++cg) {
              bf16x8 bv = *(const bf16x8*)(wB + (size_t)cg*16*512 + ks*32);
              oc[cg] = __builtin_amdgcn_mfma_f32_16x16x32_bf16(av, bv, oc[cg], 0, 0, 0);
            }
          }
#pragma unroll
          for (int cg = 0; cg < 4; ++cg) {
            int col = c0 + cg*16 + l15;
            float bias = p.dob[l*512 + col];
#pragma unroll
            for (int r = 0; r < 4; ++r)
              sm.a.Of[kg*4 + r][col] = oc[cg][r] + bias;
          }
          __syncthreads();
          for (int jr = wv; jr < 16; jr += 8) {
            int j = jt*16 + jr;
            float xin[8];
            if (l == 0) {
#pragma unroll
              for (int qq = 0; qq < 4; ++qq) {
                U8 x{ald8(h0f + j*512 + cb + qq*2)};
                xin[qq*2] = x.f[0]; xin[qq*2+1] = x.f[1];
              }
            } else {
#pragma unroll
              for (int qq = 0; qq < 4; ++qq) {
                U8 x{ald8(h2f + j*512 + cb + qq*2)};
                U8 o{ald8(ofb + j*512 + cb + qq*2)};
                xin[qq*2] = x.f[0]+o.f[0]; xin[qq*2+1] = x.f[1]+o.f[1];
              }
              wave_ln(xin, p.dln3g + (l-1)*512, p.dln3b + (l-1)*512, cb);
            }
            float v[8];
#pragma unroll
            for (int qq = 0; qq < 8; ++qq) v[qq] = xin[qq] + sm.a.Of[jr][cb+qq];
            wave_ln(v, p.dln1g + l*512, p.dln1b + l*512, cb);
#pragma unroll
            for (int qq = 0; qq < 8; ++qq) v[qq] += crossB[l*512 + cb+qq];
            wave_ln(v, p.dln2g + l*512, p.dln2b + l*512, cb);
            if (j < s) {
#pragma unroll
              for (int qq = 0; qq < 4; ++qq) {
                U8 x; x.f[0] = v[qq*2]; x.f[1] = v[qq*2+1];
                ast8(h2f + j*512 + cb + qq*2, x.u);
              }
              U8 p0, p1;
#pragma unroll
              for (int qq = 0; qq < 4; ++qq) { p0.h[qq] = f2b(v[qq]); p1.h[qq] = f2b(v[4+qq]); }
              ast8(&h2b[j*512 + cb], p0.u);
              ast8(&h2b[j*512 + cb + 4], p1.u);
            }
          }
        } else {
          // idle members: warm this layer's F1/F2 weight slices into L2
          u64 sink = 0;
#pragma unroll
          for (int k4 = 0; k4 < 4; ++k4) {
            const u64* ptr = (const u64*)(w116 + ((size_t)l*2048 + (m + k4*8)*64)*512);
            for (int i = t; i < 512; i += NT) sink += ptr[(size_t)i*16];
          }
          const u64* p2 = (const u64*)(w216 + ((size_t)l*512 + m*64)*2048);
          for (int i = t; i < 2048; i += NT) sink += p2[(size_t)i*16];
          asm volatile("" :: "v"(sink));
        }
      }
      BAR(cntG, GM, epG);
      // ======== F1: FFN1 + gelu -> ubuf ========
      {
        const int rbase = (l == NLAY-1) ? jtL*16 : 0;
        const int RN = (l == NLAY-1) ? 1 : JT;
        for (int i = t; i < RN*16*16; i += NT) {
          int j = i >> 4, cc = (i & 15)*32;
#pragma unroll
          for (int k = 0; k < 8; ++k)
            *(u64*)&sm.q.A[j][cc + k*4] = ald8(h2b + (rbase+j)*512 + cc + k*4);
        }
        __syncthreads();
        const u16* w1l = w116 + (size_t)l*2048*512;
        for (int k4 = 0; k4 < 4; ++k4) {
          int c0 = (m + k4*8)*64;
          f32x4 acc[2][4];
#pragma unroll
          for (int a2 = 0; a2 < 2; ++a2)
#pragma unroll
            for (int cg = 0; cg < 4; ++cg) acc[a2][cg] = (f32x4){0.f,0.f,0.f,0.f};
          wgemm2<512>(&sm.q.A[0][0], 520, RN, w1l + (size_t)c0*512, acc);
          for (int jl = 0; jl < RN; ++jl)
#pragma unroll
            for (int cg = 0; cg < 4; ++cg) {
              int col = c0 + cg*16 + l15;
              float bias = p.df1b[l*2048 + col];
#pragma unroll
              for (int r = 0; r < 4; ++r) {
                int j = rbase + jl*16 + kg*4 + r;
                float u = acc[jl][cg][r] + bias;
                u = 0.5f*u*(1.0f + erff(u*0.70710678118654752f));
                u16 bv = f2b(u);
                u32 ov = (u32)__shfl_xor((int)(u32)bv, 1);
                if (!(l15 & 1)) ast4(&ubuf[(size_t)j*2048 + col], (u32)bv | (ov << 16));
              }
            }
        }
      }
      BAR(cntG, GM, epG);
      // ======== F2: FFN2 -> ofb ========
      {
        const int rbase = (l == NLAY-1) ? jtL*16 : 0;
        const int RN = (l == NLAY-1) ? 1 : JT;
        for (int i = t; i < RN*16*64; i += NT) {
          int j = i >> 6, cc = (i & 63)*32;
#pragma unroll
          for (int k = 0; k < 8; ++k)
            *(u64*)&sm.f2.A[j][cc + k*4] = ald8(ubuf + (size_t)(rbase+j)*2048 + cc + k*4);
        }
        __syncthreads();
        f32x4 acc[2][4];
#pragma unroll
        for (int a2 = 0; a2 < 2; ++a2)
#pragma unroll
          for (int cg = 0; cg < 4; ++cg) acc[a2][cg] = (f32x4){0.f,0.f,0.f,0.f};
        wgemm2<2048>(&sm.f2.A[0][0], 2056, RN, w216 + ((size_t)l*512 + m*64)*2048, acc);
        for (int jl = 0; jl < RN; ++jl)
#pragma unroll
          for (int cg = 0; cg < 4; ++cg) {
            int col = m*64 + cg*16 + l15;
            float bias = p.df2b[l*512 + col];
#pragma unroll
            for (int r = 0; r < 4; ++r) {
              int j = rbase + jl*16 + kg*4 + r;
              float v = acc[jl][cg][r] + bias;
              float ov = __shfl_xor(v, 1);
              if (!(l15 & 1)) { U8 x; x.f[0] = v; x.f[1] = ov; ast8(&ofb[j*512 + col], x.u); }
            }
          }
      }
      BAR(cntG, GM, epG);
    } // layers
    // ======== FIN: LN3 + LNf of row s-1 -> out, next h0 ========
    if (m == 0 && wv == 0) {
      int j = s - 1;
      float v[8];
#pragma unroll
      for (int qq = 0; qq < 4; ++qq) {
        U8 x{ald8(h2f + j*512 + cb + qq*2)};
        U8 o{ald8(ofb + j*512 + cb + qq*2)};
        v[qq*2] = x.f[0]+o.f[0]; v[qq*2+1] = x.f[1]+o.f[1];
      }
      wave_ln(v, p.dln3g + 3*512, p.dln3b + 3*512, cb);
      wave_ln(v, p.dlnfg, p.dlnfb, cb);
#pragma unroll
      for (int qq = 0; qq < 8; ++qq)
        p.out[((size_t)b*TLEN + st)*512 + cb + qq] = v[qq];
      if (st + 1 < TLEN) {
        float nh[8];
#pragma unroll
        for (int qq = 0; qq < 8; ++qq) {
          int c = cb + qq;
          float ang = (float)(st+1) * expf((float)(c & ~1) * (-9.210340371976184f/512.0f));
          float pev = (c & 1) ? cosf(ang) : sinf(ang);
          nh[qq] = v[qq] + pev;
        }
#pragma unroll
        for (int qq = 0; qq < 4; ++qq) {
          U8 x; x.f[0] = nh[qq*2]; x.f[1] = nh[qq*2+1];
          ast8(&h0f[(st+1)*512 + cb + qq*2], x.u);
        }
        U8 p0, p1;
#pragma unroll
        for (int qq = 0; qq < 4; ++qq) { p0.h[qq] = f2b(nh[qq]); p1.h[qq] = f2b(nh[4+qq]); }
        ast8(&h0b[(st+1)*512 + cb], p0.u);
        ast8(&h0b[(st+1)*512 + cb + 4], p1.u);
      }
    }
    BAR(cntG, GM, epG);
  } // steps
}

extern "C" void kernel_launch(void* const* d_in, const int* in_sizes, int n_in,
                              void* d_out, int out_size, void* d_ws, size_t ws_size,
                              hipStream_t stream) {
  Params P;
  P.y     = (const float*)d_in[0];
  P.start = (const float*)d_in[1];
  // d_in[2] = target_length (fixed 32)
  P.eqw  = (const float*)d_in[3];  P.eqb  = (const float*)d_in[4];
  P.eow  = (const float*)d_in[5];  P.eob  = (const float*)d_in[6];
  P.ef1w = (const float*)d_in[7];  P.ef1b = (const float*)d_in[8];
  P.ef2w = (const float*)d_in[9];  P.ef2b = (const float*)d_in[10];
  P.eln1g = (const float*)d_in[11]; P.eln1b = (const float*)d_in[12];
  P.eln2g = (const float*)d_in[13]; P.eln2b = (const float*)d_in[14];
  P.elnfg = (const float*)d_in[15]; P.elnfb = (const float*)d_in[16];
  P.dqw  = (const float*)d_in[17]; P.dqb  = (const float*)d_in[18];
  P.dow  = (const float*)d_in[19]; P.dob  = (const float*)d_in[20];
  P.dxqw = (const float*)d_in[21]; P.dxqb = (const float*)d_in[22];
  P.dxow = (const float*)d_in[23]; P.dxob = (const float*)d_in[24];
  P.df1w = (const float*)d_in[25]; P.df1b = (const float*)d_in[26];
  P.df2w = (const float*)d_in[27]; P.df2b = (const float*)d_in[28];
  P.dln1g = (const float*)d_in[29]; P.dln1b = (const float*)d_in[30];
  P.dln2g = (const float*)d_in[31]; P.dln2b = (const float*)d_in[32];
  P.dln3g = (const float*)d_in[33]; P.dln3b = (const float*)d_in[34];
  P.dlnfg = (const float*)d_in[35]; P.dlnfb = (const float*)d_in[36];
  P.out = (float*)d_out;
  P.ws  = (float*)d_ws;
  hipMemsetAsync(d_ws, 0, 4096, stream);   // zero all barrier counters
  hipLaunchKernelGGL(ar_transformer, dim3(NB), dim3(NT), 0, stream, P);
}